// Round 6
// baseline (190.824 us; speedup 1.0000x reference)
//
#include <hip/hip_runtime.h>

#define TPB 256

typedef unsigned short u16;
typedef unsigned int u32;
typedef short short8 __attribute__((ext_vector_type(8)));
typedef float f32x4 __attribute__((ext_vector_type(4)));

#define KEEP(x) asm volatile("" :: "v"(x))

__device__ __forceinline__ u16 f2bf(float x) {
  union { float f; u32 u; } v;
  v.f = x;
  u32 r = v.u + 0x7FFFu + ((v.u >> 16) & 1u);
  return (u16)(r >> 16);
}

__device__ __forceinline__ float bf2f(u16 x) {
  union { u32 u; float f; } v;
  v.u = ((u32)x) << 16;
  return v.f;
}

// ---------------- prep: fold BN into bf16 weights + bf16-ize features ----------------
// w1b: [256][480] (cols>=451 zero), w2b: [256][256], w3b: [64][256] (rows>=50 zero),
// Fbf: [16][64][384] bf16
__global__ void prep_kernel(const float* __restrict__ w1, const float* __restrict__ b1,
                            const float* __restrict__ g1, const float* __restrict__ be1,
                            const float* __restrict__ m1, const float* __restrict__ v1,
                            const float* __restrict__ w2, const float* __restrict__ b2,
                            const float* __restrict__ g2, const float* __restrict__ be2,
                            const float* __restrict__ m2, const float* __restrict__ v2,
                            const float* __restrict__ w3, const float* __restrict__ b3,
                            const float* __restrict__ features,
                            u16* __restrict__ w1b, u16* __restrict__ w2b, u16* __restrict__ w3b,
                            float* __restrict__ b1p, float* __restrict__ b2p, float* __restrict__ b3p,
                            u16* __restrict__ Fbf)
{
  int i = blockIdx.x * TPB + threadIdx.x;
  if (i < 256 * 480) {
    int o = i / 480;
    int k = i - o * 480;
    float s = g1[o] * rsqrtf(v1[o] + 1e-5f);
    u16 r = 0;
    if (k < 451) r = f2bf(w1[o * 451 + k] * s);
    w1b[i] = r;
  }
  if (i < 256 * 256) {
    int o = i >> 8;
    float s = g2[o] * rsqrtf(v2[o] + 1e-5f);
    w2b[i] = f2bf(w2[i] * s);
  }
  if (i < 64 * 256) {
    int o = i >> 8;
    u16 r = 0;
    if (o < 50) r = f2bf(w3[i]);
    w3b[i] = r;
  }
  if (i < 256) {
    float s1 = g1[i] * rsqrtf(v1[i] + 1e-5f);
    b1p[i] = (b1[i] - m1[i]) * s1 + be1[i];
    float s2 = g2[i] * rsqrtf(v2[i] + 1e-5f);
    b2p[i] = (b2[i] - m2[i]) * s2 + be2[i];
  }
  if (i < 64) {
    b3p[i] = (i < 50) ? b3[i] : 0.f;
  }
  if (i < 98304) {  // 16*64*384/4
    f32x4 v = ((const f32x4*)features)[i];
    u32 lo = (u32)f2bf(v[0]) | ((u32)f2bf(v[1]) << 16);
    u32 hi = (u32)f2bf(v[2]) | ((u32)f2bf(v[3]) << 16);
    *(uint2*)&Fbf[i * 4] = make_uint2(lo, hi);
  }
}

// ---------------- gcalc: G[b][o][k] = sum_d F[b][k][d]*w1s[o][d] (k<64), no LDS ----
// 256 blocks = 16 batches x 16 ch-groups; 4 waves; wave wv = center-frag wv.
// Tail cols 64..66 = pc weights, 67..95 = 0. bias1[b][o] = b1p[o] + cat-dot.
__global__ __launch_bounds__(256, 8)
void gcalc_kernel(const u16* __restrict__ Fbf, const int* __restrict__ category,
                  const float* __restrict__ cat_embed, const u16* __restrict__ w1b,
                  const float* __restrict__ b1p,
                  u16* __restrict__ G, float* __restrict__ bias1)
{
  const int b    = blockIdx.x >> 4;
  const int og   = blockIdx.x & 15;
  const int tid  = threadIdx.x;
  const int lane = tid & 63;
  const int wv   = tid >> 6;
  const int lr   = lane & 15;
  const int lk   = (lane >> 4) * 8;
  const int r0   = (lane >> 4) * 4;
  const u16* Fb  = Fbf + b * 24576;
  const int ch   = og * 16 + lr;

  f32x4 acc = {0.f, 0.f, 0.f, 0.f};
  #pragma unroll
  for (int ks = 0; ks < 12; ++ks) {
    short8 av = *(const short8*)(Fb + (wv * 16 + lr) * 384 + ks * 32 + lk);
    short8 bv = *(const short8*)(w1b + ch * 480 + ks * 32 + lk);
    acc = __builtin_amdgcn_mfma_f32_16x16x32_bf16(av, bv, acc, 0, 0, 0);
  }
  #pragma unroll
  for (int r = 0; r < 4; ++r)
    G[(b * 256 + ch) * 96 + wv * 16 + r0 + r] = f2bf(acc[r]);

  if (tid < 16) {
    int o = og * 16 + tid;
    const u16* wr = w1b + o * 480 + 384;
    const float* ce = cat_embed + category[b] * 64;
    float a = b1p[o];
    #pragma unroll 8
    for (int j = 0; j < 64; ++j) a += bf2f(wr[j]) * ce[j];
    bias1[b * 256 + o] = a;
    u16* Go = G + (b * 256 + o) * 96;
    Go[64] = wr[64]; Go[65] = wr[65]; Go[66] = wr[66];
    #pragma unroll
    for (int k = 67; k < 96; ++k) Go[k] = 0;
  }
}

// ---------------- fused main kernel ----------------
// One block = 64 points, 256 threads = 4 waves; wave wv owns out-ch stripe [wv*64, wv*64+64).
// knn -> P_ext[64][96] in LDS. GEMM1 (K=96) -> h1 (+bias1, relu). GEMM2 -> h2 (+b2p, relu,
// in place). GEMM3 (wave = 16 ch) -> direct scattered stores.
// hbuf [64][256] u16, granule-XOR swizzle: write col ^= (row&7)<<3, read g ^= row&7.
#define LDP 104
#define LDH 256

__global__ __launch_bounds__(256, 4)
void fused_kernel(const float* __restrict__ centers, const float* __restrict__ pc,
                  const u16* __restrict__ G, const float* __restrict__ bias1,
                  const u16* __restrict__ w2b, const u16* __restrict__ w3b,
                  const float* __restrict__ b2p, const float* __restrict__ b3p,
                  float* __restrict__ out)
{
  __shared__ u16 hbuf[64 * LDH];    // 32768 B; aliases: P_ext @0 (13312), knn scr @16384
  __shared__ float centl[192];
  __shared__ float pcl[192];

  const int bx   = blockIdx.x;
  const int b    = bx >> 7;           // 128 tiles per batch
  const int n0   = (bx & 127) << 6;   // first point
  const int tid  = threadIdx.x;
  const int lane = tid & 63;
  const int wv   = tid >> 6;          // 0..3
  const int lr   = lane & 15;
  const int lk   = (lane >> 4) * 8;
  const int r0   = (lane >> 4) * 4;

  u16*   Pm   = hbuf;                              // [64][LDP] = 13312 B
  float* scrd = (float*)((char*)hbuf + 16384);     // [256][3] f32 = 3072 B
  int*   scri = (int*)((char*)hbuf + 19456);       // [256][3] i32 = 3072 B

  // ---- zero P_ext + stage centers/pc ----
  {
    u32* Pw = (u32*)Pm;
    #pragma unroll
    for (int i = 0; i < 13; ++i) Pw[tid + 256 * i] = 0;
  }
  if (tid < 192) {
    centl[tid] = centers[b * 192 + tid];
    pcl[tid]   = pc[(b * 8192 + n0) * 3 + tid];
  }
  __syncthreads();  // S1

  // ---- knn scan: 4 threads/point, 16 centers each (all 256 threads active) ----
  {
    int p = tid >> 2, c = tid & 3;
    float px = pcl[p * 3 + 0], py = pcl[p * 3 + 1], pz = pcl[p * 3 + 2];
    float p2 = px * px + py * py + pz * pz;
    float bd0 = 3.4e38f, bd1 = 3.4e38f, bd2 = 3.4e38f;
    int bi0 = 0, bi1 = 0, bi2 = 0;
    int j0 = c * 16;
    for (int j = j0; j < j0 + 16; ++j) {
      float cx = centl[j * 3 + 0], cy = centl[j * 3 + 1], cz = centl[j * 3 + 2];
      float dotv = px * cx + py * cy + pz * cz;
      float c2 = cx * cx + cy * cy + cz * cz;
      float d2 = (p2 + c2) - 2.f * dotv;
      if (d2 < bd2) {
        if (d2 < bd1) {
          if (d2 < bd0) { bd2 = bd1; bi2 = bi1; bd1 = bd0; bi1 = bi0; bd0 = d2; bi0 = j; }
          else          { bd2 = bd1; bi2 = bi1; bd1 = d2; bi1 = j; }
        } else          { bd2 = d2; bi2 = j; }
      }
    }
    scrd[tid * 3 + 0] = bd0; scrd[tid * 3 + 1] = bd1; scrd[tid * 3 + 2] = bd2;
    scri[tid * 3 + 0] = bi0; scri[tid * 3 + 1] = bi1; scri[tid * 3 + 2] = bi2;
  }
  __syncthreads();  // S2

  // ---- merge + scatter interp weights & pc into P_ext ----
  if (tid < 64) {
    float bd0 = 3.4e38f, bd1 = 3.4e38f, bd2 = 3.4e38f;
    int bi0 = 0, bi1 = 0, bi2 = 0;
    #pragma unroll
    for (int c = 0; c < 4; ++c) {
      int t = tid * 4 + c;
      #pragma unroll
      for (int s = 0; s < 3; ++s) {
        float d2 = scrd[t * 3 + s];
        int   j  = scri[t * 3 + s];
        if (d2 < bd2) {
          if (d2 < bd1) {
            if (d2 < bd0) { bd2 = bd1; bi2 = bi1; bd1 = bd0; bi1 = bi0; bd0 = d2; bi0 = j; }
            else          { bd2 = bd1; bi2 = bi1; bd1 = d2; bi1 = j; }
          } else          { bd2 = d2; bi2 = j; }
        }
      }
    }
    float dd0 = sqrtf(fmaxf(bd0, 1e-12f));
    float dd1 = sqrtf(fmaxf(bd1, 1e-12f));
    float dd2 = sqrtf(fmaxf(bd2, 1e-12f));
    float u0 = 1.f / (dd0 + 1e-8f);
    float u1 = 1.f / (dd1 + 1e-8f);
    float u2 = 1.f / (dd2 + 1e-8f);
    float inv = 1.f / (u0 + u1 + u2);
    u16* Pr = Pm + tid * LDP;
    Pr[bi0] = f2bf(u0 * inv);
    Pr[bi1] = f2bf(u1 * inv);
    Pr[bi2] = f2bf(u2 * inv);
    Pr[64] = f2bf(pcl[tid * 3 + 0]);
    Pr[65] = f2bf(pcl[tid * 3 + 1]);
    Pr[66] = f2bf(pcl[tid * 3 + 2]);
  }
  __syncthreads();  // S3

  // ---- GEMM1: P_ext [64][96] x G-stripe -> 64 ch/wave ----
  f32x4 acc[4][4];
  {
    f32x4 z = {0.f, 0.f, 0.f, 0.f};
    #pragma unroll
    for (int m = 0; m < 4; ++m)
      #pragma unroll
      for (int n = 0; n < 4; ++n) acc[m][n] = z;
  }
  #pragma unroll
  for (int ks = 0; ks < 3; ++ks) {
    short8 av[4], bv[4];
    #pragma unroll
    for (int m = 0; m < 4; ++m)
      av[m] = *(const short8*)(&Pm[(m * 16 + lr) * LDP + ks * 32 + lk]);
    #pragma unroll
    for (int n = 0; n < 4; ++n)
      bv[n] = *(const short8*)(G + (b * 256 + wv * 64 + n * 16 + lr) * 96 + ks * 32 + lk);
    #pragma unroll
    for (int m = 0; m < 4; ++m)
      #pragma unroll
      for (int n = 0; n < 4; ++n)
        acc[m][n] = __builtin_amdgcn_mfma_f32_16x16x32_bf16(av[m], bv[n], acc[m][n], 0, 0, 0);
  }
  __syncthreads();  // S4 (P_ext dead)

  // ---- epilogue 1: bias1 + relu -> h1 (swizzled) ----
  #pragma unroll
  for (int n = 0; n < 4; ++n) {
    float bb = bias1[b * 256 + wv * 64 + n * 16 + lr];
    #pragma unroll
    for (int m = 0; m < 4; ++m)
      #pragma unroll
      for (int r = 0; r < 4; ++r) {
        float v = acc[m][n][r] + bb;
        v = v > 0.f ? v : 0.f;
        int row = m * 16 + r0 + r;
        int col = (wv * 64 + n * 16 + lr) ^ ((row & 7) << 3);
        hbuf[row * LDH + col] = f2bf(v);
      }
  }
  __syncthreads();  // S5

  // ---- GEMM2: h1 [64][256] x w2b-stripe -> h2 ----
  {
    f32x4 z = {0.f, 0.f, 0.f, 0.f};
    #pragma unroll
    for (int m = 0; m < 4; ++m)
      #pragma unroll
      for (int n = 0; n < 4; ++n) acc[m][n] = z;
  }
  #pragma unroll
  for (int ks = 0; ks < 8; ++ks) {
    short8 bv[4], av[4];
    #pragma unroll
    for (int n = 0; n < 4; ++n)
      bv[n] = *(const short8*)(w2b + (wv * 64 + n * 16 + lr) * 256 + ks * 32 + lk);
    #pragma unroll
    for (int m = 0; m < 4; ++m) {
      int row = m * 16 + lr;
      int g = (ks * 4 + (lane >> 4)) ^ (row & 7);
      av[m] = *(const short8*)(&hbuf[row * LDH + g * 8]);
    }
    #pragma unroll
    for (int m = 0; m < 4; ++m)
      #pragma unroll
      for (int n = 0; n < 4; ++n)
        acc[m][n] = __builtin_amdgcn_mfma_f32_16x16x32_bf16(av[m], bv[n], acc[m][n], 0, 0, 0);
  }
  __syncthreads();  // S6

  // ---- epilogue 2: b2p + relu -> h2 in place (swizzled) ----
  #pragma unroll
  for (int n = 0; n < 4; ++n) {
    float bb = b2p[wv * 64 + n * 16 + lr];
    #pragma unroll
    for (int m = 0; m < 4; ++m)
      #pragma unroll
      for (int r = 0; r < 4; ++r) {
        float v = acc[m][n][r] + bb;
        v = v > 0.f ? v : 0.f;
        int row = m * 16 + r0 + r;
        int col = (wv * 64 + n * 16 + lr) ^ ((row & 7) << 3);
        hbuf[row * LDH + col] = f2bf(v);
      }
  }

  // ---- preload w3 fragments (wave wv -> ch wv*16..wv*16+15) across S7 ----
  short8 w3f[8];
  #pragma unroll
  for (int ks = 0; ks < 8; ++ks)
    w3f[ks] = *(const short8*)(w3b + (wv * 16 + lr) * 256 + ks * 32 + lk);
  #pragma unroll
  for (int ks = 0; ks < 8; ++ks) KEEP(w3f[ks]);
  __syncthreads();  // S7

  // ---- GEMM3: h2 x w3b -> logits, direct scattered store ----
  {
    f32x4 acc3[4];
    f32x4 z = {0.f, 0.f, 0.f, 0.f};
    #pragma unroll
    for (int m = 0; m < 4; ++m) acc3[m] = z;
    #pragma unroll
    for (int ks = 0; ks < 8; ++ks) {
      #pragma unroll
      for (int m = 0; m < 4; ++m) {
        int row = m * 16 + lr;
        int g = (ks * 4 + (lane >> 4)) ^ (row & 7);
        short8 av = *(const short8*)(&hbuf[row * LDH + g * 8]);
        acc3[m] = __builtin_amdgcn_mfma_f32_16x16x32_bf16(av, w3f[ks], acc3[m], 0, 0, 0);
      }
    }
    int c = wv * 16 + lr;
    if (c < 50) {
      float b3v = b3p[c];
      #pragma unroll
      for (int m = 0; m < 4; ++m)
        #pragma unroll
        for (int r = 0; r < 4; ++r) {
          int row = n0 + m * 16 + r0 + r;
          out[(b * 8192 + row) * 50 + c] = acc3[m][r] + b3v;
        }
    }
  }
}

extern "C" void kernel_launch(void* const* d_in, const int* in_sizes, int n_in,
                              void* d_out, int out_size, void* d_ws, size_t ws_size,
                              hipStream_t stream) {
  const float* features  = (const float*)d_in[0];
  const float* centers   = (const float*)d_in[1];
  const float* pc        = (const float*)d_in[2];
  const int*   category  = (const int*)d_in[3];
  const float* cat_embed = (const float*)d_in[4];
  const float* w1  = (const float*)d_in[5];
  const float* b1  = (const float*)d_in[6];
  const float* g1  = (const float*)d_in[7];
  const float* be1 = (const float*)d_in[8];
  const float* m1  = (const float*)d_in[9];
  const float* v1  = (const float*)d_in[10];
  const float* w2  = (const float*)d_in[11];
  const float* b2  = (const float*)d_in[12];
  const float* g2  = (const float*)d_in[13];
  const float* be2 = (const float*)d_in[14];
  const float* m2  = (const float*)d_in[15];
  const float* v2  = (const float*)d_in[16];
  const float* w3  = (const float*)d_in[17];
  const float* b3  = (const float*)d_in[18];
  float* out = (float*)d_out;

  char* ws = (char*)d_ws;
  u16*   w1b   = (u16*)(ws);              // 245760 B
  u16*   w2b   = (u16*)(ws + 245760);     // 131072 B
  u16*   w3b   = (u16*)(ws + 376832);     //  32768 B
  float* b1p   = (float*)(ws + 409600);   //   1024 B
  float* b2p   = (float*)(ws + 410624);   //   1024 B
  float* b3p   = (float*)(ws + 411648);   //   1024 B (256 used)
  u16*   G     = (u16*)(ws + 412672);     // 786432 B
  float* bias1 = (float*)(ws + 1199104);  //  16384 B
  u16*   Fbf   = (u16*)(ws + 1215488);    // 786432 B -> ends ~2.0 MB

  prep_kernel<<<480, TPB, 0, stream>>>(w1, b1, g1, be1, m1, v1,
                                       w2, b2, g2, be2, m2, v2,
                                       w3, b3, features,
                                       w1b, w2b, w3b, b1p, b2p, b3p, Fbf);
  gcalc_kernel<<<256, 256, 0, stream>>>(Fbf, category, cat_embed, w1b, b1p, G, bias1);

  fused_kernel<<<2048, 256, 0, stream>>>(centers, pc, G, bias1,
                                         w2b, w3b, b2p, b3p, out);
}

// Round 7
// 169.379 us; speedup vs baseline: 1.1266x; 1.1266x over previous
//
#include <hip/hip_runtime.h>

typedef unsigned short u16;
typedef unsigned int u32;
typedef short short8 __attribute__((ext_vector_type(8)));
typedef float f32x4 __attribute__((ext_vector_type(4)));

#define KEEP(x) asm volatile("" :: "v"(x))
#define BN_EPS 1e-5f

__device__ __forceinline__ u16 f2bf(float x) {
  union { float f; u32 u; } v;
  v.f = x;
  u32 r = v.u + 0x7FFFu + ((v.u >> 16) & 1u);
  return (u16)(r >> 16);
}

// ---------------- gcalc_all: single pre-kernel (81 blocks) ----------------
// blocks 0..63  : (b = bid>>2, och0 = (bid&3)*64) -> G[b][ch][96] + bias1[b][ch]
//                 G[ch][k<64] = sum_d F[b][k][d] * w1[ch][d]*s1;  cols 64..66 = pc-w; 67..95 = 0
//                 bias1 = (b1-m1)*s1+be1 + sum_j w1[ch][384+j]*s1*cat_embed[cat[b]][j]
// blocks 64..79 : w2b[i] = bf16(w2[i] * s2[i>>8])   (4096 elems each)
// block  80     : w3b [64][256] (rows>=50 zero) + b2p[256]
__global__ __launch_bounds__(256, 2)
void gcalc_all(const float* __restrict__ features, const int* __restrict__ category,
               const float* __restrict__ cat_embed,
               const float* __restrict__ w1, const float* __restrict__ b1,
               const float* __restrict__ g1, const float* __restrict__ be1,
               const float* __restrict__ m1, const float* __restrict__ v1,
               const float* __restrict__ w2, const float* __restrict__ g2,
               const float* __restrict__ b2, const float* __restrict__ be2,
               const float* __restrict__ m2, const float* __restrict__ v2,
               const float* __restrict__ w3,
               u16* __restrict__ G, float* __restrict__ bias1,
               u16* __restrict__ w2b, u16* __restrict__ w3b, float* __restrict__ b2p)
{
  __shared__ u16 Fs[64 * 392];   // 49152 B (only used by G-blocks)
  const int bid = blockIdx.x;
  const int tid = threadIdx.x;

  if (bid < 64) {
    const int b    = bid >> 2;
    const int och0 = (bid & 3) * 64;
    const int lane = tid & 63;
    const int wv   = tid >> 6;          // n-frag: ch och0 + wv*16 .. +15
    const int lr   = lane & 15;
    const int lk   = (lane >> 4) * 8;
    const int r0   = (lane >> 4) * 4;

    // stage F[b] as bf16 [64][392]
    const f32x4* F4 = (const f32x4*)(features + b * 24576);
    #pragma unroll
    for (int it = 0; it < 24; ++it) {
      int idx = tid + 256 * it;         // < 6144
      int c = idx / 96;
      int d4 = idx - c * 96;
      f32x4 v = F4[c * 96 + d4];
      u32 lo = (u32)f2bf(v[0]) | ((u32)f2bf(v[1]) << 16);
      u32 hi = (u32)f2bf(v[2]) | ((u32)f2bf(v[3]) << 16);
      *(uint2*)&Fs[c * 392 + d4 * 4] = make_uint2(lo, hi);
    }

    // bias1 + G tail cols for this block's 64 channels
    if (tid < 64) {
      int o = och0 + tid;
      float s1 = g1[o] * rsqrtf(v1[o] + BN_EPS);
      float acc = (b1[o] - m1[o]) * s1 + be1[o];
      const float* wr = w1 + o * 451 + 384;
      const float* ce = cat_embed + category[b] * 64;
      #pragma unroll 8
      for (int j = 0; j < 64; ++j) acc += wr[j] * s1 * ce[j];
      bias1[b * 256 + o] = acc;
      u16* Go = G + (b * 256 + o) * 96;
      Go[64] = f2bf(wr[64] * s1);
      Go[65] = f2bf(wr[65] * s1);
      Go[66] = f2bf(wr[66] * s1);
      #pragma unroll
      for (int k = 67; k < 96; ++k) Go[k] = 0;
    }
    __syncthreads();

    // GEMM: Fs [64 centers][384] x w1-row(ch) -> G[ch][center]
    const int ch = och0 + wv * 16 + lr;
    const float s1 = g1[ch] * rsqrtf(v1[ch] + BN_EPS);
    f32x4 acc[4];
    {
      f32x4 z = {0.f, 0.f, 0.f, 0.f};
      #pragma unroll
      for (int m = 0; m < 4; ++m) acc[m] = z;
    }
    #pragma unroll
    for (int ks = 0; ks < 12; ++ks) {
      const float* wr = w1 + ch * 451 + ks * 32 + lk;
      short8 bv;
      #pragma unroll
      for (int e = 0; e < 8; ++e) bv[e] = (short)f2bf(wr[e] * s1);
      #pragma unroll
      for (int m = 0; m < 4; ++m) {
        short8 av = *(const short8*)(&Fs[(m * 16 + lr) * 392 + ks * 32 + lk]);
        acc[m] = __builtin_amdgcn_mfma_f32_16x16x32_bf16(av, bv, acc[m], 0, 0, 0);
      }
    }
    #pragma unroll
    for (int m = 0; m < 4; ++m)
      #pragma unroll
      for (int r = 0; r < 4; ++r)
        G[(b * 256 + ch) * 96 + m * 16 + r0 + r] = f2bf(acc[m][r]);

  } else if (bid < 80) {
    // w2b: 4096 elems per block
    int base = (bid - 64) * 4096;
    #pragma unroll
    for (int e = 0; e < 16; ++e) {
      int i = base + e * 256 + tid;
      int o = i >> 8;
      float s2 = g2[o] * rsqrtf(v2[o] + BN_EPS);
      w2b[i] = f2bf(w2[i] * s2);
    }
  } else {
    // w3b + b2p
    #pragma unroll
    for (int e = 0; e < 64; ++e) {
      int i = e * 256 + tid;
      int o = i >> 8;
      w3b[i] = (o < 50) ? f2bf(w3[i]) : (u16)0;
    }
    {
      float s2 = g2[tid] * rsqrtf(v2[tid] + BN_EPS);
      b2p[tid] = (b2[tid] - m2[tid]) * s2 + be2[tid];
    }
  }
}

// ---------------- fused main kernel (R4-proven structure) ----------------
// One block = 128 points, 512 threads = 8 waves.
// knn -> P_ext[128][96] in LDS. GEMM1: P_ext x G (K=96) -> h1 (+bias1, relu).
// GEMM2 -> h2 (+b2p, relu, in place). GEMM3 -> direct scattered stores.
// h-buffer XOR-swizzled: col ^= ((row>>2)&7)<<3 (u16), g ^= (row>>2)&7 (b128).
#define LDP 104
#define LDH 264

__global__ __launch_bounds__(512, 4)
void fused_kernel(const float* __restrict__ centers, const float* __restrict__ pc,
                  const u16* __restrict__ G, const float* __restrict__ bias1,
                  const u16* __restrict__ w2b, const u16* __restrict__ w3b,
                  const float* __restrict__ b2p, const float* __restrict__ b3,
                  float* __restrict__ out)
{
  __shared__ u16 hbuf[128 * LDH];   // 67584 B; aliases: P_ext @0, knn scr @32768
  __shared__ float centl[192];
  __shared__ float pcl[384];

  // bijective XCD swizzle (1024 blocks, 8 XCDs): same-batch tiles share an XCD's L2
  const int bx   = ((blockIdx.x & 7) << 7) | (blockIdx.x >> 3);
  const int b    = bx >> 6;
  const int n0   = (bx & 63) << 7;
  const int tid  = threadIdx.x;
  const int lane = tid & 63;
  const int wv   = tid >> 6;
  const int lr   = lane & 15;
  const int lk   = (lane >> 4) * 8;
  const int r0   = (lane >> 4) * 4;

  u16*   Pm   = hbuf;                              // [128][LDP]
  float* scrd = (float*)((char*)hbuf + 32768);     // [512][3]
  int*   scri = (int*)((char*)hbuf + 40960);       // [512][3]

  // ---- preload this wave's G fragments (complete during knn) ----
  short8 bvG[3][2];
  #pragma unroll
  for (int ks = 0; ks < 3; ++ks)
    #pragma unroll
    for (int n = 0; n < 2; ++n)
      bvG[ks][n] = *(const short8*)(G + (b * 256 + wv * 32 + n * 16 + lr) * 96 + ks * 32 + lk);

  // ---- zero P_ext + stage centers/pc ----
  {
    u32* Pw = (u32*)Pm;
    #pragma unroll
    for (int i = 0; i < 13; ++i) Pw[tid + 512 * i] = 0;
  }
  if (tid < 192) centl[tid] = centers[b * 192 + tid];
  if (tid < 384) pcl[tid] = pc[(b * 8192 + n0) * 3 + tid];
  __syncthreads();  // S1

  // ---- knn scan: 4 threads/point, 16 centers each ----
  {
    int p = tid >> 2, c = tid & 3;
    float px = pcl[p * 3 + 0], py = pcl[p * 3 + 1], pz = pcl[p * 3 + 2];
    float p2 = px * px + py * py + pz * pz;
    float bd0 = 3.4e38f, bd1 = 3.4e38f, bd2 = 3.4e38f;
    int bi0 = 0, bi1 = 0, bi2 = 0;
    int j0 = c * 16;
    for (int j = j0; j < j0 + 16; ++j) {
      float cx = centl[j * 3 + 0], cy = centl[j * 3 + 1], cz = centl[j * 3 + 2];
      float dotv = px * cx + py * cy + pz * cz;
      float c2 = cx * cx + cy * cy + cz * cz;
      float d2 = (p2 + c2) - 2.f * dotv;
      if (d2 < bd2) {
        if (d2 < bd1) {
          if (d2 < bd0) { bd2 = bd1; bi2 = bi1; bd1 = bd0; bi1 = bi0; bd0 = d2; bi0 = j; }
          else          { bd2 = bd1; bi2 = bi1; bd1 = d2; bi1 = j; }
        } else          { bd2 = d2; bi2 = j; }
      }
    }
    scrd[tid * 3 + 0] = bd0; scrd[tid * 3 + 1] = bd1; scrd[tid * 3 + 2] = bd2;
    scri[tid * 3 + 0] = bi0; scri[tid * 3 + 1] = bi1; scri[tid * 3 + 2] = bi2;
  }
  __syncthreads();  // S2

  // ---- merge + scatter interp weights & pc into P_ext ----
  if (tid < 128) {
    float bd0 = 3.4e38f, bd1 = 3.4e38f, bd2 = 3.4e38f;
    int bi0 = 0, bi1 = 0, bi2 = 0;
    #pragma unroll
    for (int c = 0; c < 4; ++c) {
      int t = tid * 4 + c;
      #pragma unroll
      for (int s = 0; s < 3; ++s) {
        float d2 = scrd[t * 3 + s];
        int   j  = scri[t * 3 + s];
        if (d2 < bd2) {
          if (d2 < bd1) {
            if (d2 < bd0) { bd2 = bd1; bi2 = bi1; bd1 = bd0; bi1 = bi0; bd0 = d2; bi0 = j; }
            else          { bd2 = bd1; bi2 = bi1; bd1 = d2; bi1 = j; }
          } else          { bd2 = d2; bi2 = j; }
        }
      }
    }
    float dd0 = sqrtf(fmaxf(bd0, 1e-12f));
    float dd1 = sqrtf(fmaxf(bd1, 1e-12f));
    float dd2 = sqrtf(fmaxf(bd2, 1e-12f));
    float u0 = 1.f / (dd0 + 1e-8f);
    float u1 = 1.f / (dd1 + 1e-8f);
    float u2 = 1.f / (dd2 + 1e-8f);
    float inv = 1.f / (u0 + u1 + u2);
    u16* Pr = Pm + tid * LDP;
    Pr[bi0] = f2bf(u0 * inv);
    Pr[bi1] = f2bf(u1 * inv);
    Pr[bi2] = f2bf(u2 * inv);
    Pr[64] = f2bf(pcl[tid * 3 + 0]);
    Pr[65] = f2bf(pcl[tid * 3 + 1]);
    Pr[66] = f2bf(pcl[tid * 3 + 2]);
  }
  KEEP(bvG[0][0]); KEEP(bvG[0][1]); KEEP(bvG[1][0]);
  KEEP(bvG[1][1]); KEEP(bvG[2][0]); KEEP(bvG[2][1]);
  __syncthreads();  // S3

  // ---- GEMM1: P_ext [128][96] x G-stripe -> 32 ch/wave ----
  f32x4 acc[8][2];
  {
    f32x4 z = {0.f, 0.f, 0.f, 0.f};
    #pragma unroll
    for (int m = 0; m < 8; ++m) { acc[m][0] = z; acc[m][1] = z; }
  }
  #pragma unroll
  for (int ks = 0; ks < 3; ++ks) {
    short8 av[8];
    #pragma unroll
    for (int m = 0; m < 8; ++m)
      av[m] = *(const short8*)(&Pm[(m * 16 + lr) * LDP + ks * 32 + lk]);
    #pragma unroll
    for (int m = 0; m < 8; ++m)
      #pragma unroll
      for (int n = 0; n < 2; ++n)
        acc[m][n] = __builtin_amdgcn_mfma_f32_16x16x32_bf16(av[m], bvG[ks][n], acc[m][n], 0, 0, 0);
  }
  __syncthreads();  // S4 (P_ext dead)

  // ---- epilogue 1: bias1 + relu -> h1 (swizzled) ----
  #pragma unroll
  for (int n = 0; n < 2; ++n) {
    float bb = bias1[b * 256 + wv * 32 + n * 16 + lr];
    #pragma unroll
    for (int m = 0; m < 8; ++m)
      #pragma unroll
      for (int r = 0; r < 4; ++r) {
        float v = acc[m][n][r] + bb;
        v = v > 0.f ? v : 0.f;
        int row = m * 16 + r0 + r;
        int col = (wv * 32 + n * 16 + lr) ^ (((row >> 2) & 7) << 3);
        hbuf[row * LDH + col] = f2bf(v);
      }
  }
  __syncthreads();  // S5

  // ---- GEMM2: h1 [128][256] x w2b-stripe -> h2 ----
  {
    f32x4 z = {0.f, 0.f, 0.f, 0.f};
    #pragma unroll
    for (int m = 0; m < 8; ++m) { acc[m][0] = z; acc[m][1] = z; }
  }
  #pragma unroll
  for (int ks = 0; ks < 8; ++ks) {
    short8 bv[2];
    #pragma unroll
    for (int n = 0; n < 2; ++n)
      bv[n] = *(const short8*)(w2b + (wv * 32 + n * 16 + lr) * 256 + ks * 32 + lk);
    short8 av[8];
    #pragma unroll
    for (int m = 0; m < 8; ++m) {
      int row = m * 16 + lr;
      int g = (ks * 4 + (lane >> 4)) ^ ((row >> 2) & 7);
      av[m] = *(const short8*)(&hbuf[row * LDH + g * 8]);
    }
    #pragma unroll
    for (int m = 0; m < 8; ++m)
      #pragma unroll
      for (int n = 0; n < 2; ++n)
        acc[m][n] = __builtin_amdgcn_mfma_f32_16x16x32_bf16(av[m], bv[n], acc[m][n], 0, 0, 0);
  }
  __syncthreads();  // S6

  // ---- epilogue 2: b2p + relu -> h2 in place (swizzled) ----
  #pragma unroll
  for (int n = 0; n < 2; ++n) {
    float bb = b2p[wv * 32 + n * 16 + lr];
    #pragma unroll
    for (int m = 0; m < 8; ++m)
      #pragma unroll
      for (int r = 0; r < 4; ++r) {
        float v = acc[m][n][r] + bb;
        v = v > 0.f ? v : 0.f;
        int row = m * 16 + r0 + r;
        int col = (wv * 32 + n * 16 + lr) ^ (((row >> 2) & 7) << 3);
        hbuf[row * LDH + col] = f2bf(v);
      }
  }

  // ---- preload w3 fragments across S7 ----
  const int wm = wv & 3;
  const int wn = wv >> 2;
  short8 w3f[8][2];
  #pragma unroll
  for (int ks = 0; ks < 8; ++ks)
    #pragma unroll
    for (int j = 0; j < 2; ++j)
      w3f[ks][j] = *(const short8*)(w3b + (wn * 32 + j * 16 + lr) * 256 + ks * 32 + lk);
  #pragma unroll
  for (int ks = 0; ks < 8; ++ks) { KEEP(w3f[ks][0]); KEEP(w3f[ks][1]); }
  __syncthreads();  // S7

  // ---- GEMM3: h2 x w3b -> logits, direct scattered store ----
  {
    f32x4 acc3[2][2];
    f32x4 z = {0.f, 0.f, 0.f, 0.f};
    acc3[0][0] = z; acc3[0][1] = z; acc3[1][0] = z; acc3[1][1] = z;
    #pragma unroll
    for (int ks = 0; ks < 8; ++ks) {
      #pragma unroll
      for (int mi = 0; mi < 2; ++mi) {
        int row = (wm * 2 + mi) * 16 + lr;
        int g = (ks * 4 + (lane >> 4)) ^ ((row >> 2) & 7);
        short8 av = *(const short8*)(&hbuf[row * LDH + g * 8]);
        #pragma unroll
        for (int j = 0; j < 2; ++j)
          acc3[mi][j] = __builtin_amdgcn_mfma_f32_16x16x32_bf16(av, w3f[ks][j], acc3[mi][j], 0, 0, 0);
      }
    }
    #pragma unroll
    for (int j = 0; j < 2; ++j) {
      int c = wn * 32 + j * 16 + lr;
      if (c < 50) {
        float b3v = b3[c];
        #pragma unroll
        for (int mi = 0; mi < 2; ++mi)
          #pragma unroll
          for (int r = 0; r < 4; ++r) {
            int row = n0 + (wm * 2 + mi) * 16 + r0 + r;
            out[(b * 8192 + row) * 50 + c] = acc3[mi][j][r] + b3v;
          }
      }
    }
  }
}

extern "C" void kernel_launch(void* const* d_in, const int* in_sizes, int n_in,
                              void* d_out, int out_size, void* d_ws, size_t ws_size,
                              hipStream_t stream) {
  const float* features  = (const float*)d_in[0];
  const float* centers   = (const float*)d_in[1];
  const float* pc        = (const float*)d_in[2];
  const int*   category  = (const int*)d_in[3];
  const float* cat_embed = (const float*)d_in[4];
  const float* w1  = (const float*)d_in[5];
  const float* b1  = (const float*)d_in[6];
  const float* g1  = (const float*)d_in[7];
  const float* be1 = (const float*)d_in[8];
  const float* m1  = (const float*)d_in[9];
  const float* v1  = (const float*)d_in[10];
  const float* w2  = (const float*)d_in[11];
  const float* b2  = (const float*)d_in[12];
  const float* g2  = (const float*)d_in[13];
  const float* be2 = (const float*)d_in[14];
  const float* m2  = (const float*)d_in[15];
  const float* v2  = (const float*)d_in[16];
  const float* w3  = (const float*)d_in[17];
  const float* b3  = (const float*)d_in[18];
  float* out = (float*)d_out;

  char* ws = (char*)d_ws;
  u16*   w2b   = (u16*)(ws);              // 131072 B
  u16*   w3b   = (u16*)(ws + 131072);     //  32768 B
  float* b2p   = (float*)(ws + 163840);   //   1024 B
  u16*   G     = (u16*)(ws + 164864);     // 786432 B
  float* bias1 = (float*)(ws + 951296);   //  16384 B -> ends 967680

  gcalc_all<<<81, 256, 0, stream>>>(features, category, cat_embed,
                                    w1, b1, g1, be1, m1, v1,
                                    w2, g2, b2, be2, m2, v2, w3,
                                    G, bias1, w2b, w3b, b2p);

  fused_kernel<<<1024, 512, 0, stream>>>(centers, pc, G, bias1,
                                         w2b, w3b, b2p, b3, out);
}